// Round 8
// baseline (299.284 us; speedup 1.0000x reference)
//
#include <hip/hip_runtime.h>

// DeepSeek MoE gate. Round 8: 2 WGs/CU via E-split.
// WG = 128 tok x 128 experts x 3584 K (splitK=2), BK=32, 8 waves (4wr x 2wc),
// per-wave 32x64, acc=64 AGPR. LDS 64 KB: B dbuf 2x16K (DMA via
// global_load_lds) + A dbuf 2x16K (reg-staged f32->f16 hi/lo, chunk-major
// layout, conflict-free). ONE barrier per K-step (write buf^1 / read buf).
// Counted vmcnt(2): B DMA lands by the barrier, A loads stay in flight.
// launch_bounds(512,4) -> 128-reg cap -> 16 waves/CU (4/SIMD).
// XCD map: same (tb,slice) pair of ehalf-WGs -> same XCD (X fetched once/pair,
// blob quarter pairs stay L2-resident).

#define TTOK 16384
#define EEXP 256
#define HDIM 7168
#define BM 128
#define BE 128
#define BK 32
#define SPLITK 2
#define KSLICE (HDIM / SPLITK)  // 3584
#define NSTEP (KSLICE / BK)     // 112
#define NTHR 512
#define LDS_BYTES 65536         // B0,B1 @0,16K; A0,A1 @32K,48K (hi 8K + lo 8K)
#define EPI_LDS (64 * 257 * 4)  // 65792

typedef __attribute__((ext_vector_type(4))) float f32x4;
typedef __attribute__((ext_vector_type(8))) _Float16 h8;

__device__ __forceinline__ void gload_lds16(const void* g, void* l) {
  typedef const __attribute__((address_space(1))) unsigned int gu32;
  typedef __attribute__((address_space(3))) unsigned int lu32;
  __builtin_amdgcn_global_load_lds((gu32*)g, (lu32*)l, 16, 0, 0);
}

// ---------------------------------------------------------------------------
// Kernel 1: W -> blob[slice][ehalf][kc'][eb'][hi/lo][lane]: per (slice,ehalf,
// kc) a 16 KB contiguous chunk of 16 fragment-granules (8 eb' x hi/lo).
// Fragment: expert e = eb*16+(lane&15), k = kc*32+(lane>>4)*8+j.
// ---------------------------------------------------------------------------
__global__ __launch_bounds__(64) void pack_w_kernel(const float* __restrict__ W,
                                                    _Float16* __restrict__ blob) {
  const int kcg = blockIdx.x;    // 0..223
  const int eb = blockIdx.y;     // 0..15
  const int lane = threadIdx.x;  // 0..63
  const int e = eb * 16 + (lane & 15);
  const int k0 = kcg * 32 + (lane >> 4) * 8;
  const float* src = W + (size_t)e * HDIM + k0;
  h8 hi, lo;
#pragma unroll
  for (int j = 0; j < 8; ++j) {
    float x = src[j];
    _Float16 h = (_Float16)x;
    hi[j] = h;
    lo[j] = (_Float16)((x - (float)h) * 2048.0f);  // exact residual, out of denormals
  }
  const int slice = kcg / NSTEP, kcl = kcg % NSTEP;
  const int ehalf = eb >> 3, ebl = eb & 7;
  char* dst = (char*)blob + ((size_t)(slice * 2 + ehalf) * NSTEP + kcl) * 16384 +
              (ebl * 2) * 1024 + lane * 16;
  *(h8*)dst = hi;
  *(h8*)(dst + 1024) = lo;
}

// ---------------------------------------------------------------------------
// Kernel 2: split-K, split-E GEMM -> f32 partial logits.
// ---------------------------------------------------------------------------
__global__ __launch_bounds__(NTHR, 4) void gate_kernel(
    const float* __restrict__ X, const _Float16* __restrict__ Wblob,
    float* __restrict__ part) {
  extern __shared__ char smem[];

  const int bid = blockIdx.x;                 // 0..511
  const int slice = (bid & 7) >> 2;           // XCDs 0-3: slice 0; 4-7: slice 1
  const int ehalf = (bid >> 3) & 1;           // paired ehalfs 8 apart -> same XCD
  const int tb = ((bid >> 4) << 2) | (bid & 3);  // 0..127
  const int tok0 = tb * BM;
  const int kbase = slice * KSLICE;
  const char* blobs = (const char*)Wblob +
                      ((size_t)(slice * 2 + ehalf) * NSTEP) * 16384;

  const int tid = threadIdx.x;
  const int lane = tid & 63;
  const int wid = tid >> 6;
  const int wr = wid >> 1;  // 0..3 : 32-token stripe
  const int wc = wid & 1;   // 0..1 : 64-expert stripe

  f32x4 ra[2];  // A prefetch: 8 f32/thread

  f32x4 acc1[2][4], acc2[2][4];
#pragma unroll
  for (int m = 0; m < 2; ++m)
#pragma unroll
    for (int n = 0; n < 4; ++n) {
      acc1[m][n] = (f32x4){0.f, 0.f, 0.f, 0.f};
      acc2[m][n] = (f32x4){0.f, 0.f, 0.f, 0.f};
    }

  auto LOADA = [&](int T) {
    const float* p = X + (size_t)(tok0 + (tid >> 2)) * HDIM + kbase + T * BK +
                     (tid & 3) * 8;
    ra[0] = *(const f32x4*)p;
    ra[1] = *(const f32x4*)(p + 4);
  };

  auto STAGEB = [&](int T, int buf) {  // 16 granules of 1 KB; 2 per wave
    const char* gs = blobs + (size_t)T * 16384 + lane * 16;
    char* lb = smem + buf * 16384 + lane * 16;
    gload_lds16(gs + (wid * 2) * 1024, lb + (wid * 2) * 1024);
    gload_lds16(gs + (wid * 2 + 1) * 1024, lb + (wid * 2 + 1) * 1024);
  };

  auto STOREA = [&](int buf) {  // chunk-major A plane: [4 kc][128 row][16B]
    h8 hi, lo;
#pragma unroll
    for (int half = 0; half < 2; ++half) {
      const f32x4 v = ra[half];
#pragma unroll
      for (int j = 0; j < 4; ++j) {
        const float x = v[j];
        const _Float16 h = (_Float16)x;
        hi[half * 4 + j] = h;
        lo[half * 4 + j] = (_Float16)((x - (float)h) * 2048.0f);
      }
    }
    char* ah = smem + 32768 + buf * 16384;
    const int row = tid >> 2, q = tid & 3;
    *(h8*)(ah + q * 2048 + row * 16) = hi;
    *(h8*)(ah + 8192 + q * 2048 + row * 16) = lo;
  };

  auto PHASE = [&](int buf) {
    const char* ahp = smem + 32768 + buf * 16384;
    const char* bb = smem + buf * 16384;
    h8 ah[2], al[2];
#pragma unroll
    for (int m = 0; m < 2; ++m) {
      const int r_ = wr * 32 + m * 16 + (lane & 15);
      const int ao_ = (lane >> 4) * 2048 + r_ * 16;
      ah[m] = *(const h8*)(ahp + ao_);
      al[m] = *(const h8*)(ahp + 8192 + ao_);
    }
    __builtin_amdgcn_s_setprio(1);
#pragma unroll
    for (int n = 0; n < 4; ++n) {  // B frags just-in-time: low reg pressure
      const int bo_ = ((wc * 4 + n) * 2) * 1024 + lane * 16;
      const h8 bh = *(const h8*)(bb + bo_);
      const h8 bl = *(const h8*)(bb + bo_ + 1024);
#pragma unroll
      for (int m = 0; m < 2; ++m) {
        acc1[m][n] = __builtin_amdgcn_mfma_f32_16x16x32_f16(ah[m], bh, acc1[m][n], 0, 0, 0);
        acc2[m][n] = __builtin_amdgcn_mfma_f32_16x16x32_f16(ah[m], bl, acc2[m][n], 0, 0, 0);
        acc2[m][n] = __builtin_amdgcn_mfma_f32_16x16x32_f16(al[m], bh, acc2[m][n], 0, 0, 0);
      }
    }
    __builtin_amdgcn_s_setprio(0);
  };

  // Prologue: FIFO discipline -> [B0 x2, ra1 x2] outstanding at the wait.
  LOADA(0);
  asm volatile("" ::: "memory");
  STAGEB(0, 0);
  asm volatile("" ::: "memory");
  STOREA(0);  // auto-waits ra(0) with vmcnt(2): B0 stays in flight
  LOADA(1);
  asm volatile("s_waitcnt vmcnt(2) lgkmcnt(0)" ::: "memory");  // B0 done, ra1 flying
  __builtin_amdgcn_s_barrier();

  int p = 0;
#pragma unroll 1
  for (int T = 0; T < NSTEP; ++T) {
    if (T + 1 < NSTEP) {
      STAGEB(T + 1, p ^ 1);  // buf p^1 readers finished at last barrier
      asm volatile("" ::: "memory");
      STOREA(p ^ 1);         // auto-waits ra(T+1) (older than B DMA): counted
      if (T + 2 < NSTEP) LOADA(T + 2);
    }
    PHASE(p);
    if (T + 2 < NSTEP) {
      asm volatile("s_waitcnt vmcnt(2) lgkmcnt(0)" ::: "memory");  // B(T+1) done
    } else {
      asm volatile("s_waitcnt vmcnt(0) lgkmcnt(0)" ::: "memory");
    }
    __builtin_amdgcn_s_barrier();
    p ^= 1;
  }

  // Partial f32 logits: part[slice][token][expert(256)], our 128-col half.
  // C/D layout: col = lane&15, row = (lane>>4)*4 + reg.
  float* pbase = part + ((size_t)slice * TTOK + tok0) * EEXP + ehalf * BE;
#pragma unroll
  for (int m = 0; m < 2; ++m)
#pragma unroll
    for (int n = 0; n < 4; ++n) {
      const int e = wc * 64 + n * 16 + (lane & 15);
      const int t0 = wr * 32 + m * 16 + (lane >> 4) * 4;
#pragma unroll
      for (int r = 0; r < 4; ++r)
        pbase[(size_t)(t0 + r) * EEXP + e] =
            acc1[m][n][r] + acc2[m][n][r] * (1.0f / 2048.0f);
    }
}

// ---------------------------------------------------------------------------
// Kernel 3: epilogue. 64 tokens/WG: sum 2 partials, sigmoid+bias -> LDS,
// then 64 lanes do per-token group-limited top-k. (Proven R3/R7.)
// ---------------------------------------------------------------------------
__global__ __launch_bounds__(256) void epilogue_kernel(
    const float* __restrict__ part, const float* __restrict__ bias,
    float* __restrict__ outw, float* __restrict__ outi) {
  extern __shared__ float sc[];  // [64][257]
  const int tid = threadIdx.x;
  const long t0 = (long)blockIdx.x * 64;

  const int e4 = (tid & 63) * 4;
  const int rsub = tid >> 6;
  const f32x4 bv = *(const f32x4*)(bias + e4);
#pragma unroll
  for (int rr = 0; rr < 16; ++rr) {
    const int row = rr * 4 + rsub;
    const f32x4 a = *(const f32x4*)(part + (t0 + row) * EEXP + e4);
    const f32x4 c = *(const f32x4*)(part + ((long)TTOK + t0 + row) * EEXP + e4);
#pragma unroll
    for (int j = 0; j < 4; ++j) {
      const float v = a[j] + c[j];
      sc[row * 257 + e4 + j] = 1.0f / (1.0f + expf(-v)) + bv[j];
    }
  }
  __syncthreads();

  if (tid < 64) {
    const float* s = sc + tid * 257;
    float gmax[8];
#pragma unroll
    for (int g = 0; g < 8; ++g) {
      float mx = -1e30f;
      for (int j = 0; j < 32; ++j) mx = fmaxf(mx, s[g * 32 + j]);
      gmax[g] = mx;
    }
    // top-4 groups (strict > keeps lowest index on ties, matching lax.top_k)
    unsigned selmask = 0;
    for (int it = 0; it < 4; ++it) {
      float best = -1e30f;
      int bi = 0;
      for (int g = 0; g < 8; ++g)
        if (!((selmask >> g) & 1) && gmax[g] > best) {
          best = gmax[g];
          bi = g;
        }
      selmask |= 1u << bi;
    }
    // stable top-8 over masked scores (masked-out groups contribute 0.0)
    float vals[8];
    int idx[8];
#pragma unroll
    for (int j = 0; j < 8; ++j) {
      vals[j] = -1e30f;
      idx[j] = 0;
    }
    for (int e = 0; e < 256; ++e) {
      const float v = ((selmask >> (e >> 5)) & 1) ? s[e] : 0.0f;
      if (v > vals[7]) {
        int p = 7;
        while (p > 0 && v > vals[p - 1]) {
          vals[p] = vals[p - 1];
          idx[p] = idx[p - 1];
          --p;
        }
        vals[p] = v;
        idx[p] = e;
      }
    }
    float ssum = 0.0f;
#pragma unroll
    for (int j = 0; j < 8; ++j) ssum += vals[j];
    const float den = ssum + 1e-6f;
    const long tg = t0 + tid;
#pragma unroll
    for (int j = 0; j < 8; ++j) {
      outw[tg * 8 + j] = vals[j] / den;
      outi[tg * 8 + j] = (float)idx[j];  // indices written as f32 values
    }
  }
}

extern "C" void kernel_launch(void* const* d_in, const int* in_sizes, int n_in,
                              void* d_out, int out_size, void* d_ws, size_t ws_size,
                              hipStream_t stream) {
  const float* X = (const float*)d_in[0];     // [16384,7168] f32
  const float* W = (const float*)d_in[1];     // [256,7168] f32
  const float* bias = (const float*)d_in[2];  // [256] f32

  _Float16* wblob = (_Float16*)d_ws;                              // 7.34 MB
  float* part = (float*)((char*)d_ws + (size_t)EEXP * HDIM * 4);  // 33.6 MB

  float* outw = (float*)d_out;            // [16384,8]
  float* outi = outw + (size_t)TTOK * 8;  // [16384,8] as f32 values

  hipFuncSetAttribute((const void*)gate_kernel,
                      hipFuncAttributeMaxDynamicSharedMemorySize, LDS_BYTES);
  hipFuncSetAttribute((const void*)epilogue_kernel,
                      hipFuncAttributeMaxDynamicSharedMemorySize, EPI_LDS);

  pack_w_kernel<<<dim3(HDIM / 32, EEXP / 16), 64, 0, stream>>>(W, wblob);
  gate_kernel<<<SPLITK * 2 * (TTOK / BM), NTHR, LDS_BYTES, stream>>>(X, wblob, part);
  epilogue_kernel<<<TTOK / 64, 256, EPI_LDS, stream>>>(part, bias, outw, outi);
}

// Round 10
// 292.238 us; speedup vs baseline: 1.0241x; 1.0241x over previous
//
#include <hip/hip_runtime.h>

// DeepSeek MoE gate. Round 10 = Round 9's B-prefetch-distance-2 with the
// WAR hazard fixed: LOADA(T+2) is issued only AFTER STOREA(pa^1) has
// consumed ra(T+1) (R9 clobbered ra before conversion -> wrong logits).
// WG = 128 tok x 128 experts x 3584 K (splitK=2), BK=32, 8 waves (4wr x 2wc).
// LDS 80 KB: B TRIPLE buffer 3x16K @0/16K/32K (global_load_lds DMA issued
// 2 steps ahead) + A dbuf 2x16K @48K/64K (reg-staged f32->f16 hi/lo).
// End-of-step: counted vmcnt(4) (B(T+2) x2 + ra(T+2) x2 stay in flight) +
// lgkmcnt(0) + s_barrier. 2 WGs/CU (160 KB), grid 512.
// XCD map: paired ehalf-WGs with same (tb,slice) -> same XCD.

#define TTOK 16384
#define EEXP 256
#define HDIM 7168
#define BM 128
#define BE 128
#define BK 32
#define SPLITK 2
#define KSLICE (HDIM / SPLITK)  // 3584
#define NSTEP (KSLICE / BK)     // 112
#define NTHR 512
#define LDS_BYTES 81920         // B0,B1,B2 @0,16K,32K; A0,A1 @48K,64K
#define ABASE 49152
#define EPI_LDS (64 * 257 * 4)  // 65792

typedef __attribute__((ext_vector_type(4))) float f32x4;
typedef __attribute__((ext_vector_type(8))) _Float16 h8;

__device__ __forceinline__ void gload_lds16(const void* g, void* l) {
  typedef const __attribute__((address_space(1))) unsigned int gu32;
  typedef __attribute__((address_space(3))) unsigned int lu32;
  __builtin_amdgcn_global_load_lds((gu32*)g, (lu32*)l, 16, 0, 0);
}

// ---------------------------------------------------------------------------
// Kernel 1: W -> blob[slice][ehalf][kc'][eb'][hi/lo][lane]: per (slice,ehalf,
// kc) a 16 KB contiguous chunk of 16 fragment-granules (8 eb' x hi/lo).
// Fragment: expert e = eb*16+(lane&15), k = kc*32+(lane>>4)*8+j.
// ---------------------------------------------------------------------------
__global__ __launch_bounds__(64) void pack_w_kernel(const float* __restrict__ W,
                                                    _Float16* __restrict__ blob) {
  const int kcg = blockIdx.x;    // 0..223
  const int eb = blockIdx.y;     // 0..15
  const int lane = threadIdx.x;  // 0..63
  const int e = eb * 16 + (lane & 15);
  const int k0 = kcg * 32 + (lane >> 4) * 8;
  const float* src = W + (size_t)e * HDIM + k0;
  h8 hi, lo;
#pragma unroll
  for (int j = 0; j < 8; ++j) {
    float x = src[j];
    _Float16 h = (_Float16)x;
    hi[j] = h;
    lo[j] = (_Float16)((x - (float)h) * 2048.0f);  // exact residual, out of denormals
  }
  const int slice = kcg / NSTEP, kcl = kcg % NSTEP;
  const int ehalf = eb >> 3, ebl = eb & 7;
  char* dst = (char*)blob + ((size_t)(slice * 2 + ehalf) * NSTEP + kcl) * 16384 +
              (ebl * 2) * 1024 + lane * 16;
  *(h8*)dst = hi;
  *(h8*)(dst + 1024) = lo;
}

// ---------------------------------------------------------------------------
// Kernel 2: split-K, split-E GEMM -> f32 partial logits.
// ---------------------------------------------------------------------------
__global__ __launch_bounds__(NTHR, 4) void gate_kernel(
    const float* __restrict__ X, const _Float16* __restrict__ Wblob,
    float* __restrict__ part) {
  extern __shared__ char smem[];

  const int bid = blockIdx.x;                    // 0..511
  const int slice = (bid & 7) >> 2;              // XCDs 0-3: slice 0; 4-7: slice 1
  const int ehalf = (bid >> 3) & 1;              // paired ehalfs 8 apart -> same XCD
  const int tb = ((bid >> 4) << 2) | (bid & 3);  // 0..127
  const int tok0 = tb * BM;
  const int kbase = slice * KSLICE;
  const char* blobs = (const char*)Wblob +
                      ((size_t)(slice * 2 + ehalf) * NSTEP) * 16384;

  const int tid = threadIdx.x;
  const int lane = tid & 63;
  const int wid = tid >> 6;
  const int wr = wid >> 1;  // 0..3 : 32-token stripe
  const int wc = wid & 1;   // 0..1 : 64-expert stripe

  f32x4 ra[2];  // A prefetch: 8 f32/thread

  f32x4 acc1[2][4], acc2[2][4];
#pragma unroll
  for (int m = 0; m < 2; ++m)
#pragma unroll
    for (int n = 0; n < 4; ++n) {
      acc1[m][n] = (f32x4){0.f, 0.f, 0.f, 0.f};
      acc2[m][n] = (f32x4){0.f, 0.f, 0.f, 0.f};
    }

  auto LOADA = [&](int T) {
    const float* p = X + (size_t)(tok0 + (tid >> 2)) * HDIM + kbase + T * BK +
                     (tid & 3) * 8;
    ra[0] = *(const f32x4*)p;
    ra[1] = *(const f32x4*)(p + 4);
  };

  auto STAGEB = [&](int T, int buf) {  // 16 granules of 1 KB; 2 per wave
    const char* gs = blobs + (size_t)T * 16384 + lane * 16;
    char* lb = smem + buf * 16384 + lane * 16;
    gload_lds16(gs + (wid * 2) * 1024, lb + (wid * 2) * 1024);
    gload_lds16(gs + (wid * 2 + 1) * 1024, lb + (wid * 2 + 1) * 1024);
  };

  auto STOREA = [&](int buf) {  // chunk-major A plane: [4 kc][128 row][16B]
    h8 hi, lo;
#pragma unroll
    for (int half = 0; half < 2; ++half) {
      const f32x4 v = ra[half];
#pragma unroll
      for (int j = 0; j < 4; ++j) {
        const float x = v[j];
        const _Float16 h = (_Float16)x;
        hi[half * 4 + j] = h;
        lo[half * 4 + j] = (_Float16)((x - (float)h) * 2048.0f);
      }
    }
    char* ah = smem + ABASE + buf * 16384;
    const int row = tid >> 2, q = tid & 3;
    *(h8*)(ah + q * 2048 + row * 16) = hi;
    *(h8*)(ah + 8192 + q * 2048 + row * 16) = lo;
  };

  auto PHASE = [&](int pa, int pb) {
    const char* ahp = smem + ABASE + pa * 16384;
    const char* bb = smem + pb * 16384;
    h8 ah[2], al[2];
#pragma unroll
    for (int m = 0; m < 2; ++m) {
      const int r_ = wr * 32 + m * 16 + (lane & 15);
      const int ao_ = (lane >> 4) * 2048 + r_ * 16;
      ah[m] = *(const h8*)(ahp + ao_);
      al[m] = *(const h8*)(ahp + 8192 + ao_);
    }
    __builtin_amdgcn_s_setprio(1);
#pragma unroll
    for (int n = 0; n < 4; ++n) {  // B frags just-in-time: low reg pressure
      const int bo_ = ((wc * 4 + n) * 2) * 1024 + lane * 16;
      const h8 bh = *(const h8*)(bb + bo_);
      const h8 bl = *(const h8*)(bb + bo_ + 1024);
#pragma unroll
      for (int m = 0; m < 2; ++m) {
        acc1[m][n] = __builtin_amdgcn_mfma_f32_16x16x32_f16(ah[m], bh, acc1[m][n], 0, 0, 0);
        acc2[m][n] = __builtin_amdgcn_mfma_f32_16x16x32_f16(ah[m], bl, acc2[m][n], 0, 0, 0);
        acc2[m][n] = __builtin_amdgcn_mfma_f32_16x16x32_f16(al[m], bh, acc2[m][n], 0, 0, 0);
      }
    }
    __builtin_amdgcn_s_setprio(0);
  };

  // Prologue: B0,B1 staged; A0 converted; leave {B1, ra1} in flight.
  STAGEB(0, 0);
  LOADA(0);
  STAGEB(1, 1);
  STOREA(0);  // implicit wait retires ra0 (and B0, which is older)
  LOADA(1);
  asm volatile("s_waitcnt vmcnt(4) lgkmcnt(0)" ::: "memory");
  __builtin_amdgcn_s_barrier();

  int pa = 0, pb = 0;
#pragma unroll 1
  for (int T = 0; T < NSTEP; ++T) {
    const bool p2 = (T + 2 < NSTEP);
    if (p2) {
      int sb = pb + 2;
      if (sb >= 3) sb -= 3;
      STAGEB(T + 2, sb);  // DMA issued 2 steps ahead; lands into retired buffer
    }
    PHASE(pa, pb);
    if (T + 1 < NSTEP) {
      STOREA(pa ^ 1);        // consumes ra(T+1) FIRST (implicit counted wait)
      if (p2) LOADA(T + 2);  // THEN refill ra -- no WAR clobber (R9's bug)
      if (p2)
        asm volatile("s_waitcnt vmcnt(4) lgkmcnt(0)" ::: "memory");
      else
        asm volatile("s_waitcnt vmcnt(0) lgkmcnt(0)" ::: "memory");
      __builtin_amdgcn_s_barrier();
    }
    pa ^= 1;
    pb = (pb == 2) ? 0 : pb + 1;
  }

  // Partial f32 logits: part[slice][token][expert(256)], our 128-col half.
  // C/D layout: col = lane&15, row = (lane>>4)*4 + reg.
  float* pbase = part + ((size_t)slice * TTOK + tok0) * EEXP + ehalf * BE;
#pragma unroll
  for (int m = 0; m < 2; ++m)
#pragma unroll
    for (int n = 0; n < 4; ++n) {
      const int e = wc * 64 + n * 16 + (lane & 15);
      const int t0 = wr * 32 + m * 16 + (lane >> 4) * 4;
#pragma unroll
      for (int r = 0; r < 4; ++r)
        pbase[(size_t)(t0 + r) * EEXP + e] =
            acc1[m][n][r] + acc2[m][n][r] * (1.0f / 2048.0f);
    }
}

// ---------------------------------------------------------------------------
// Kernel 3: epilogue. 64 tokens/WG: sum 2 partials, sigmoid+bias -> LDS,
// then 64 lanes do per-token group-limited top-k. (Proven R3/R7/R8.)
// ---------------------------------------------------------------------------
__global__ __launch_bounds__(256) void epilogue_kernel(
    const float* __restrict__ part, const float* __restrict__ bias,
    float* __restrict__ outw, float* __restrict__ outi) {
  extern __shared__ float sc[];  // [64][257]
  const int tid = threadIdx.x;
  const long t0 = (long)blockIdx.x * 64;

  const int e4 = (tid & 63) * 4;
  const int rsub = tid >> 6;
  const f32x4 bv = *(const f32x4*)(bias + e4);
#pragma unroll
  for (int rr = 0; rr < 16; ++rr) {
    const int row = rr * 4 + rsub;
    const f32x4 a = *(const f32x4*)(part + (t0 + row) * EEXP + e4);
    const f32x4 c = *(const f32x4*)(part + ((long)TTOK + t0 + row) * EEXP + e4);
#pragma unroll
    for (int j = 0; j < 4; ++j) {
      const float v = a[j] + c[j];
      sc[row * 257 + e4 + j] = 1.0f / (1.0f + expf(-v)) + bv[j];
    }
  }
  __syncthreads();

  if (tid < 64) {
    const float* s = sc + tid * 257;
    float gmax[8];
#pragma unroll
    for (int g = 0; g < 8; ++g) {
      float mx = -1e30f;
      for (int j = 0; j < 32; ++j) mx = fmaxf(mx, s[g * 32 + j]);
      gmax[g] = mx;
    }
    // top-4 groups (strict > keeps lowest index on ties, matching lax.top_k)
    unsigned selmask = 0;
    for (int it = 0; it < 4; ++it) {
      float best = -1e30f;
      int bi = 0;
      for (int g = 0; g < 8; ++g)
        if (!((selmask >> g) & 1) && gmax[g] > best) {
          best = gmax[g];
          bi = g;
        }
      selmask |= 1u << bi;
    }
    // stable top-8 over masked scores (masked-out groups contribute 0.0)
    float vals[8];
    int idx[8];
#pragma unroll
    for (int j = 0; j < 8; ++j) {
      vals[j] = -1e30f;
      idx[j] = 0;
    }
    for (int e = 0; e < 256; ++e) {
      const float v = ((selmask >> (e >> 5)) & 1) ? s[e] : 0.0f;
      if (v > vals[7]) {
        int p = 7;
        while (p > 0 && v > vals[p - 1]) {
          vals[p] = vals[p - 1];
          idx[p] = idx[p - 1];
          --p;
        }
        vals[p] = v;
        idx[p] = e;
      }
    }
    float ssum = 0.0f;
#pragma unroll
    for (int j = 0; j < 8; ++j) ssum += vals[j];
    const float den = ssum + 1e-6f;
    const long tg = t0 + tid;
#pragma unroll
    for (int j = 0; j < 8; ++j) {
      outw[tg * 8 + j] = vals[j] / den;
      outi[tg * 8 + j] = (float)idx[j];  // indices written as f32 values
    }
  }
}

extern "C" void kernel_launch(void* const* d_in, const int* in_sizes, int n_in,
                              void* d_out, int out_size, void* d_ws, size_t ws_size,
                              hipStream_t stream) {
  const float* X = (const float*)d_in[0];     // [16384,7168] f32
  const float* W = (const float*)d_in[1];     // [256,7168] f32
  const float* bias = (const float*)d_in[2];  // [256] f32

  _Float16* wblob = (_Float16*)d_ws;                              // 7.34 MB
  float* part = (float*)((char*)d_ws + (size_t)EEXP * HDIM * 4);  // 33.6 MB

  float* outw = (float*)d_out;            // [16384,8]
  float* outi = outw + (size_t)TTOK * 8;  // [16384,8] as f32 values

  hipFuncSetAttribute((const void*)gate_kernel,
                      hipFuncAttributeMaxDynamicSharedMemorySize, LDS_BYTES);
  hipFuncSetAttribute((const void*)epilogue_kernel,
                      hipFuncAttributeMaxDynamicSharedMemorySize, EPI_LDS);

  pack_w_kernel<<<dim3(HDIM / 32, EEXP / 16), 64, 0, stream>>>(W, wblob);
  gate_kernel<<<SPLITK * 2 * (TTOK / BM), NTHR, LDS_BYTES, stream>>>(X, wblob, part);
  epilogue_kernel<<<TTOK / 64, 256, EPI_LDS, stream>>>(part, bias, outw, outi);
}